// Round 12
// baseline (19.633 us; speedup 1.0000x reference)
//
#include <hip/hip_runtime.h>
#include <hip/hip_bf16.h>

// PSRoIAlign: features [B, C=D*G*G, H, W] fp32, rois [N,5], out [N, D, G, G].
// G=7, SR=2, D=10, H=W=160.
//
// Round 12: sorted-scatter (R11, 18.97us) + d-pair batching.
//  Thread = (roi, sample, d-pair): coordinate math + slist/param loads are
//  computed ONCE per 2 d-planes (R11 recomputed per plane), halving the VALU
//  prologue and metadata traffic while keeping 4 scattered loads in flight
//  per thread and ~30 waves/CU (grid = 49 bins x 5 d-pairs x 8 y-chunks =
//  1960 blocks x 256 threads; 64 sorted ROIs per block = exactly 1
//  unit/thread). HBM footprint unchanged (compulsory scattered lines).
//  Sort kernel unchanged from R11 (counting-sort per ph by (rb, ylo0),
//  params stored in sorted order).

#define G 7
#define SR 2
#define D_OUT 10
#define HH 160
#define WW 160
#define SORTB 512
#define NSPLIT 8
#define DPG 2              // d-planes per thread

typedef float f2_u __attribute__((ext_vector_type(2), aligned(4)));

__global__ __launch_bounds__(SORTB) void psroi_sort_kernel(
        const float* __restrict__ rois,
        const int* __restrict__ stride_p,
        int N,
        float4* __restrict__ params_s, int* __restrict__ slist) {
    __shared__ int cnt[320];
    __shared__ int off[320];
    int ph  = blockIdx.x;
    int tid = threadIdx.x;

    for (int k = tid; k < 320; k += SORTB) cnt[k] = 0;
    __syncthreads();

    int iv = stride_p[0];
    float stride_f = (iv > 0 && iv <= 65536) ? (float)iv : __int_as_float(iv);
    float spatial_scale = 1.0f / stride_f;

    // pass 1: histogram over (rb, ylo0)
    for (int r = tid; r < N; r += SORTB) {
        const float* roi = rois + (size_t)r * 5;
        int   rb = (int)roi[0];
        float sh = roi[2] * spatial_scale - 0.5f;
        float eh = roi[4] * spatial_scale - 0.5f;
        float bh = fmaxf(eh - sh, 0.1f) * (1.0f / (float)G);
        float ys0  = sh + ((float)ph + 0.25f) * bh;
        int   ylo0 = min((int)floorf(fmaxf(ys0, 0.0f)), HH - 1);
        atomicAdd(&cnt[rb * HH + ylo0], 1);
    }
    __syncthreads();

    // exclusive prefix sum over 320 buckets: wave 0, 5 buckets per lane
    if (tid < 64) {
        int base = tid * 5;
        int s0 = cnt[base], s1 = cnt[base + 1], s2 = cnt[base + 2],
            s3 = cnt[base + 3], s4 = cnt[base + 4];
        int tot = s0 + s1 + s2 + s3 + s4;
        int scan = tot;
        for (int d = 1; d < 64; d <<= 1) {
            int v = __shfl_up(scan, d);
            if (tid >= d) scan += v;
        }
        int ex = scan - tot;
        off[base]     = ex;
        off[base + 1] = ex + s0;
        off[base + 2] = ex + s0 + s1;
        off[base + 3] = ex + s0 + s1 + s2;
        off[base + 4] = ex + s0 + s1 + s2 + s3;
    }
    __syncthreads();

    // pass 2: scatter sorted entries + params in sorted order
    for (int r = tid; r < N; r += SORTB) {
        const float* roi = rois + (size_t)r * 5;
        int   rb = (int)roi[0];
        float sw = roi[1] * spatial_scale - 0.5f;
        float sh = roi[2] * spatial_scale - 0.5f;
        float ew = roi[3] * spatial_scale - 0.5f;
        float eh = roi[4] * spatial_scale - 0.5f;
        float bh = fmaxf(eh - sh, 0.1f) * (1.0f / (float)G);
        float bw = fmaxf(ew - sw, 0.1f) * (1.0f / (float)G);
        float ys0  = sh + ((float)ph + 0.25f) * bh;
        int   ylo0 = min((int)floorf(fmaxf(ys0, 0.0f)), HH - 1);
        int pos = atomicAdd(&off[rb * HH + ylo0], 1);
        slist[(size_t)ph * N + pos]    = (rb << 16) | r;
        params_s[(size_t)ph * N + pos] = make_float4(sw, sh, bh, bw);
    }
}

__global__ __launch_bounds__(256) void psroi_gather_kernel(
        const float* __restrict__ feat,
        const float4* __restrict__ params_s, const int* __restrict__ slist,
        int N, int C,
        float* __restrict__ out) {
    // blk = ((c49*5) + dg)*NSPLIT + q
    int blk = blockIdx.x;
    int q   = blk & (NSPLIT - 1);
    int t   = blk / NSPLIT;
    int dg  = t % (D_OUT / DPG);
    int c49 = t / (D_OUT / DPG);
    int ph  = c49 / G;
    int pw  = c49 - ph * G;
    int d0  = dg * DPG;

    int nq    = (N + NSPLIT - 1) / NSPLIT;
    int lbase = q * nq;
    int count = min(nq, N - lbase);
    if (count <= 0) return;

    const int*    lst = slist    + (size_t)ph * N + lbase;
    const float4* ps  = params_s + (size_t)ph * N + lbase;
    const size_t  HW  = (size_t)HH * WW;

    int u = threadIdx.x;                  // units = count*4 <= 256
    int s  = u & 3;
    int li = u >> 2;
    if (li >= count) return;              // whole quads drop together

    int e  = lst[li];
    int r  = e & 0xffff;
    int rb = e >> 16;
    float4 pr = ps[li];                   // sw, sh, bh, bw (coalesced)

    float offy = (s & 2) ? 0.75f : 0.25f;
    float offx = (s & 1) ? 0.75f : 0.25f;
    float y = pr.y + ((float)ph + offy) * pr.z;
    float x = pr.x + ((float)pw + offx) * pr.w;
    bool vy = (y > -1.0f) && (y < (float)HH);
    bool vx = (x > -1.0f) && (x < (float)WW);

    float cy = fmaxf(y, 0.0f);
    int  ylo = min((int)floorf(cy), HH - 1);
    int  yhi = min(ylo + 1, HH - 1);
    float ly = (ylo >= HH - 1) ? 0.0f : (cy - (float)ylo);
    float hy = 1.0f - ly;

    float cx = fmaxf(x, 0.0f);
    int  xlo = min((int)floorf(cx), WW - 1);
    float lx = (xlo >= WW - 1) ? 0.0f : (cx - (float)xlo);
    float hx = 1.0f - lx;

    float acc[DPG];
#pragma unroll
    for (int j = 0; j < DPG; ++j) acc[j] = 0.0f;

    if (vy && vx) {
        int xbase = min(xlo, WW - 2);
        bool clamped = (xlo != xbase);
        int o0 = ylo * WW + xbase;
        int o1 = yhi * WW + xbase;
        const float* plane = feat + ((size_t)rb * C + (size_t)(d0 * 49 + c49)) * HW;
#pragma unroll
        for (int j = 0; j < DPG; ++j) {
            f2_u p0 = *(const f2_u*)(plane + o0);
            f2_u p1 = *(const f2_u*)(plane + o1);
            float v00 = clamped ? p0.y : p0.x;
            float v10 = clamped ? p1.y : p1.x;
            acc[j] = hy * hx * v00 + hy * lx * p0.y
                   + ly * hx * v10 + ly * lx * p1.y;
            plane += (size_t)49 * HW;     // next d-plane, same (ph,pw)
        }
    }

#pragma unroll
    for (int j = 0; j < DPG; ++j) {
        float v = acc[j];
        v += __shfl_xor(v, 1);
        v += __shfl_xor(v, 2);
        if (s == 0)
            out[(size_t)r * C + (size_t)(d0 + j) * 49 + c49] = v * 0.25f;
    }
}

extern "C" void kernel_launch(void* const* d_in, const int* in_sizes, int n_in,
                              void* d_out, int out_size, void* d_ws, size_t ws_size,
                              hipStream_t stream) {
    const float* rois = (const float*)d_in[0];
    const float* feat = (const float*)d_in[1];
    const int*   strd = (const int*)d_in[2];
    float* out = (float*)d_out;

    int N = in_sizes[0] / 5;
    const int C = D_OUT * G * G;                 // 490

    float4* params_s = (float4*)d_ws;            // G * N float4
    int*    slist    = (int*)(params_s + (size_t)G * N);

    psroi_sort_kernel<<<G, SORTB, 0, stream>>>(rois, strd, N, params_s, slist);

    int gridB = 49 * (D_OUT / DPG) * NSPLIT;     // 1960
    psroi_gather_kernel<<<gridB, 256, 0, stream>>>(feat, params_s, slist, N, C, out);
}

// Round 13
// 19.077 us; speedup vs baseline: 1.0292x; 1.0292x over previous
//
#include <hip/hip_runtime.h>
#include <hip/hip_bf16.h>

// PSRoIAlign: features [B, C=D*G*G, H, W] fp32, rois [N,5], out [N, D, G, G].
// G=7, SR=2, D=10, H=W=160.
//
// Round 13: RESTORE R11 (best: 18.97us). R12's d-pair batching regressed
// (19.63) — per-thread plane-straddling broke the sort's y-window locality.
// Final structure: sorted-scatter.
//  Kernel A (7 blocks, one per ph): counting-sort ROIs by (rb, ylo0(ph))
//  (320 buckets, wave-0 shfl scan); slist + params written in sorted order.
//  Kernel B (C*4 = 1960 blocks): quad per sorted ROI, 2 float2 gathers per
//  sample, quad-shfl reduce, one exact write per (roi, c). ~30 waves/CU,
//  2 units/thread unrolled for MLP. Bound: compulsory scattered-line HBM
//  fetch (~51MB at random-granule rate) — confirmed by R6 warm/cold counters
//  and the R3/R4/R5/R9/R12 neutral-or-regress ledger.

#define G 7
#define SR 2
#define D_OUT 10
#define HH 160
#define WW 160
#define SORTB 512
#define NSPLIT 4

typedef float f2_u __attribute__((ext_vector_type(2), aligned(4)));

__global__ __launch_bounds__(SORTB) void psroi_sort_kernel(
        const float* __restrict__ rois,
        const int* __restrict__ stride_p,
        int N,
        float4* __restrict__ params_s, int* __restrict__ slist) {
    __shared__ int cnt[320];
    __shared__ int off[320];
    int ph  = blockIdx.x;
    int tid = threadIdx.x;

    for (int k = tid; k < 320; k += SORTB) cnt[k] = 0;
    __syncthreads();

    int iv = stride_p[0];
    float stride_f = (iv > 0 && iv <= 65536) ? (float)iv : __int_as_float(iv);
    float spatial_scale = 1.0f / stride_f;

    // pass 1: histogram
    for (int r = tid; r < N; r += SORTB) {
        const float* roi = rois + (size_t)r * 5;
        int   rb = (int)roi[0];
        float sh = roi[2] * spatial_scale - 0.5f;
        float eh = roi[4] * spatial_scale - 0.5f;
        float bh = fmaxf(eh - sh, 0.1f) * (1.0f / (float)G);
        float ys0  = sh + ((float)ph + 0.25f) * bh;
        int   ylo0 = min((int)floorf(fmaxf(ys0, 0.0f)), HH - 1);
        atomicAdd(&cnt[rb * HH + ylo0], 1);
    }
    __syncthreads();

    // exclusive prefix sum over 320 buckets: wave 0, 5 buckets per lane
    if (tid < 64) {
        int base = tid * 5;
        int s0 = cnt[base], s1 = cnt[base + 1], s2 = cnt[base + 2],
            s3 = cnt[base + 3], s4 = cnt[base + 4];
        int tot = s0 + s1 + s2 + s3 + s4;
        int scan = tot;
        for (int d = 1; d < 64; d <<= 1) {
            int v = __shfl_up(scan, d);
            if (tid >= d) scan += v;
        }
        int ex = scan - tot;
        off[base]     = ex;
        off[base + 1] = ex + s0;
        off[base + 2] = ex + s0 + s1;
        off[base + 3] = ex + s0 + s1 + s2;
        off[base + 4] = ex + s0 + s1 + s2 + s3;
    }
    __syncthreads();

    // pass 2: scatter sorted entries + params in sorted order
    for (int r = tid; r < N; r += SORTB) {
        const float* roi = rois + (size_t)r * 5;
        int   rb = (int)roi[0];
        float sw = roi[1] * spatial_scale - 0.5f;
        float sh = roi[2] * spatial_scale - 0.5f;
        float ew = roi[3] * spatial_scale - 0.5f;
        float eh = roi[4] * spatial_scale - 0.5f;
        float bh = fmaxf(eh - sh, 0.1f) * (1.0f / (float)G);
        float bw = fmaxf(ew - sw, 0.1f) * (1.0f / (float)G);
        float ys0  = sh + ((float)ph + 0.25f) * bh;
        int   ylo0 = min((int)floorf(fmaxf(ys0, 0.0f)), HH - 1);
        int pos = atomicAdd(&off[rb * HH + ylo0], 1);
        slist[(size_t)ph * N + pos]    = (rb << 16) | r;
        params_s[(size_t)ph * N + pos] = make_float4(sw, sh, bh, bw);
    }
}

__global__ __launch_bounds__(256) void psroi_gather_kernel(
        const float* __restrict__ feat,
        const float4* __restrict__ params_s, const int* __restrict__ slist,
        int N, int C,
        float* __restrict__ out) {
    int blk = blockIdx.x;
    int q   = blk & (NSPLIT - 1);
    int c   = blk / NSPLIT;
    int ph  = (c / G) % G;
    int pw  = c % G;

    int nq    = (N + NSPLIT - 1) / NSPLIT;
    int lbase = q * nq;
    int count = min(nq, N - lbase);
    if (count <= 0) return;

    const int*    lst = slist    + (size_t)ph * N + lbase;
    const float4* ps  = params_s + (size_t)ph * N + lbase;
    const size_t  HW  = (size_t)HH * WW;

    int units = count * 4;
#pragma unroll
    for (int k = 0; k < 2; ++k) {
        int u = threadIdx.x + k * 256;
        if (u >= units) continue;          // whole quads drop together
        int s  = u & 3;
        int li = u >> 2;
        int e  = lst[li];
        int r  = e & 0xffff;
        int rb = e >> 16;
        float4 pr = ps[li];                // sw, sh, bh, bw (coalesced)

        float offy = (s & 2) ? 0.75f : 0.25f;
        float offx = (s & 1) ? 0.75f : 0.25f;
        float y = pr.y + ((float)ph + offy) * pr.z;
        float x = pr.x + ((float)pw + offx) * pr.w;
        bool vy = (y > -1.0f) && (y < (float)HH);
        bool vx = (x > -1.0f) && (x < (float)WW);

        float cy = fmaxf(y, 0.0f);
        int  ylo = min((int)floorf(cy), HH - 1);
        int  yhi = min(ylo + 1, HH - 1);
        float ly = (ylo >= HH - 1) ? 0.0f : (cy - (float)ylo);
        float hy = 1.0f - ly;

        float cx = fmaxf(x, 0.0f);
        int  xlo = min((int)floorf(cx), WW - 1);
        float lx = (xlo >= WW - 1) ? 0.0f : (cx - (float)xlo);
        float hx = 1.0f - lx;

        float val = 0.0f;
        if (vy && vx) {
            int xbase = min(xlo, WW - 2);
            const float* plane = feat + ((size_t)rb * C + c) * HW;
            f2_u p0 = *(const f2_u*)(plane + ylo * WW + xbase);
            f2_u p1 = *(const f2_u*)(plane + yhi * WW + xbase);
            bool clamped = (xlo != xbase);
            float v00 = clamped ? p0.y : p0.x;
            float v10 = clamped ? p1.y : p1.x;
            val = hy * hx * v00 + hy * lx * p0.y
                + ly * hx * v10 + ly * lx * p1.y;
        }
        val += __shfl_xor(val, 1);
        val += __shfl_xor(val, 2);
        if (s == 0) out[(size_t)r * C + c] = val * 0.25f;
    }
}

extern "C" void kernel_launch(void* const* d_in, const int* in_sizes, int n_in,
                              void* d_out, int out_size, void* d_ws, size_t ws_size,
                              hipStream_t stream) {
    const float* rois = (const float*)d_in[0];
    const float* feat = (const float*)d_in[1];
    const int*   strd = (const int*)d_in[2];
    float* out = (float*)d_out;

    int N = in_sizes[0] / 5;
    const int C = D_OUT * G * G;                 // 490

    float4* params_s = (float4*)d_ws;            // G * N float4
    int*    slist    = (int*)(params_s + (size_t)G * N);

    psroi_sort_kernel<<<G, SORTB, 0, stream>>>(rois, strd, N, params_s, slist);
    psroi_gather_kernel<<<C * NSPLIT, 256, 0, stream>>>(feat, params_s, slist, N, C, out);
}